// Round 3
// baseline (167.266 us; speedup 1.0000x reference)
//
#include <hip/hip_runtime.h>
#include <hip/hip_bf16.h>

#define E_ 8
#define B_ 8
#define S_ 2048
#define D_ 512
#define R_ 128
#define M_TOT (B_ * S_)   // 16384

typedef __attribute__((ext_vector_type(8))) short bf16x8;
typedef __attribute__((ext_vector_type(4))) float f32x4;

__device__ __forceinline__ void gload_lds16(void* lds, const void* g) {
  __builtin_amdgcn_global_load_lds(
      (const __attribute__((address_space(1))) void*)g,
      (__attribute__((address_space(3))) void*)lds, 16, 0, 0);
}

// ---------------------------------------------------------------------------
// Kernel 1: W[e] cols 0..128 = rotation-touched part of proj_w[e] @ Rm[e].
// All Givens planes are (0, k+1) -> per-row recurrence over k.
// ---------------------------------------------------------------------------
__global__ __launch_bounds__(512) void build_w_rot(
    const float* __restrict__ theta, const float* __restrict__ pw,
    __hip_bfloat16* __restrict__ Wb) {
  int e = blockIdx.x;
  int t = threadIdx.x;  // 0..511 = row
  __shared__ float cs[R_], ss[R_];
  __shared__ float Pch[512][33];            // +1 pad: conflict-free
  __shared__ __hip_bfloat16 Wch[512][34];   // 17-dword stride: 2-way max
  if (t < R_) {
    float a = tanhf(theta[e * R_ + t]) * 0.1f;
    cs[t] = cosf(a);
    ss[t] = sinf(a);
  }
  const float* Pe = pw + (size_t)e * D_ * D_;
  __hip_bfloat16* We = Wb + (size_t)e * D_ * D_;
  float u = Pe[(size_t)t * D_];  // P[t][0]
  __syncthreads();
  for (int c = 0; c < 4; ++c) {
    for (int i = t; i < 512 * 32; i += 512) {
      int row = i >> 5, col = i & 31;
      Pch[row][col] = Pe[(size_t)row * D_ + 1 + 32 * c + col];
    }
    __syncthreads();
#pragma unroll
    for (int kk = 0; kk < 32; ++kk) {
      int k = 32 * c + kk;
      float pj = Pch[t][kk];
      Wch[t][kk] = __float2bfloat16(cs[k] * pj - ss[k] * u);
      u = cs[k] * u + ss[k] * pj;
    }
    __syncthreads();
    for (int i = t; i < 512 * 32; i += 512) {
      int row = i >> 5, col = i & 31;
      We[(size_t)row * D_ + 1 + 32 * c + col] = Wch[row][col];
    }
    __syncthreads();
  }
  We[(size_t)t * D_] = __float2bfloat16(u);
}

// ---------------------------------------------------------------------------
// Kernel 2 (fused): x f32->bf16 (float4) + W tail cols 129..511 from proj_w.
// ---------------------------------------------------------------------------
__global__ void conv_fused(const float* __restrict__ x,
                           const float* __restrict__ pw,
                           __hip_bfloat16* __restrict__ xb,
                           __hip_bfloat16* __restrict__ Wb) {
  constexpr int NX = M_TOT * D_ / 4;   // x float4 groups
  int i = blockIdx.x * blockDim.x + threadIdx.x;
  if (i < NX) {
    float4 v = ((const float4*)x)[i];
    union { short4 s; __hip_bfloat16 h[4]; } u;
    u.h[0] = __float2bfloat16(v.x);
    u.h[1] = __float2bfloat16(v.y);
    u.h[2] = __float2bfloat16(v.z);
    u.h[3] = __float2bfloat16(v.w);
    ((short4*)xb)[i] = u.s;
  } else {
    int g = i - NX;                    // over E*D*D/4 groups
    int gidx = g & 127;                // group within a row; d = gidx*4..+3
    if (gidx < 32) return;             // d <= 127: owned by build_w_rot
    float4 v = ((const float4*)pw)[g];
    union { short4 s; __hip_bfloat16 h[4]; } u;
    u.h[0] = __float2bfloat16(v.x);
    u.h[1] = __float2bfloat16(v.y);
    u.h[2] = __float2bfloat16(v.z);
    u.h[3] = __float2bfloat16(v.w);
    if (gidx > 32) {
      ((short4*)Wb)[g] = u.s;          // d = 132..511 region, full group
    } else {                           // gidx==32: d=128..131, write 129..131
      Wb[(size_t)g * 4 + 1] = u.h[1];
      Wb[(size_t)g * 4 + 2] = u.h[2];
      Wb[(size_t)g * 4 + 3] = u.h[3];
    }
  }
}

// ---------------------------------------------------------------------------
// Kernel 3: out[e] = Xb @ Wb[e]^T  (NT GEMM). 256x256 tile, BK=64, 8 waves.
// Conflict-free k-chunked LDS layout [kc][row][8] staged via per-lane-strided
// global_load_lds sources (linear LDS dest). 2-buffer pipeline, counted
// vmcnt(8) (T4), 2 barriers/tile, setprio around MFMA (T5), XCD swizzle (T1).
// ---------------------------------------------------------------------------
__global__ __launch_bounds__(512, 2) void gemm_xw(
    const __hip_bfloat16* __restrict__ Xb,   // [M_TOT][512]
    const __hip_bfloat16* __restrict__ Wb,   // [E][512][512] rows=o, cols=d
    float* __restrict__ out)                 // [E][M_TOT][512]
{
  constexpr int BM = 256, BN = 256, BK = 64;
  constexpr int KD = D_, ND = D_;
  constexpr int NT = KD / BK;  // 8
  // [buf][kc][row][8] : fragment reads are row-contiguous 16B -> conflict-free
  __shared__ __align__(16) __hip_bfloat16 As[2][8][256][8];  // 64 KB
  __shared__ __align__(16) __hip_bfloat16 Bs[2][8][256][8];  // 64 KB

  // T1: bijective XCD-chunked swizzle, mt-major (A-panel + W reuse per XCD).
  int bx = blockIdx.x;                 // 1024 blocks, 1024%8==0
  int swz = (bx & 7) * 128 + (bx >> 3);
  int mt = swz >> 4;          // 0..63
  int e  = (swz >> 1) & 7;    // 0..7
  int nt = swz & 1;           // 0..1

  int tid = threadIdx.x;
  int wave = tid >> 6, lane = tid & 63;
  int lr = lane & 15, lk = lane >> 4;
  int wm = wave >> 2, wn = wave & 3;   // 2 x 4 waves, each owns 128x64 of C

  const __hip_bfloat16* Ag = Xb + (size_t)(mt * BM) * KD;
  const __hip_bfloat16* Bg = Wb + ((size_t)e * ND + (size_t)nt * BN) * KD;

  f32x4 acc[8][4];
#pragma unroll
  for (int i = 0; i < 8; ++i)
#pragma unroll
    for (int j = 0; j < 4; ++j) acc[i][j] = (f32x4){0.f, 0.f, 0.f, 0.f};

  // per-lane LDS fragment read bases (chunk lk, this wave's row band)
  const __hip_bfloat16* aB[2] = {&As[0][lk][wm * 128 + lr][0],
                                 &As[1][lk][wm * 128 + lr][0]};
  const __hip_bfloat16* bB[2] = {&Bs[0][lk][wn * 64 + lr][0],
                                 &Bs[1][lk][wn * 64 + lr][0]};

  // stage tile t into buf: wave stages k-chunk kc==wave, 4 row-blocks of 64.
  // LDS dest lane-linear (row*16B); global src per-lane strided (m173).
#define STAGE(buf, t)                                                        \
  {                                                                          \
    _Pragma("unroll") for (int rb = 0; rb < 4; ++rb) {                       \
      gload_lds16(&As[buf][wave][rb * 64][0],                                \
                  Ag + (size_t)(rb * 64 + lane) * KD + (t) * BK + wave * 8); \
      gload_lds16(&Bs[buf][wave][rb * 64][0],                                \
                  Bg + (size_t)(rb * 64 + lane) * KD + (t) * BK + wave * 8); \
    }                                                                        \
  }

#define COMPUTE(buf)                                                         \
  {                                                                          \
    _Pragma("unroll") for (int ks = 0; ks < 2; ++ks) {                       \
      bf16x8 bfr[4];                                                         \
      _Pragma("unroll") for (int ni = 0; ni < 4; ++ni)                       \
          bfr[ni] = *(const bf16x8*)(bB[buf] + ks * 8192 + ni * 128);        \
      _Pragma("unroll") for (int mh = 0; mh < 2; ++mh) {                     \
        bf16x8 af[4];                                                        \
        _Pragma("unroll") for (int m4 = 0; m4 < 4; ++m4)                     \
            af[m4] = *(const bf16x8*)(aB[buf] + ks * 8192 +                  \
                                      (mh * 4 + m4) * 128);                  \
        __builtin_amdgcn_s_setprio(1);                                       \
        _Pragma("unroll") for (int m4 = 0; m4 < 4; ++m4)                     \
            _Pragma("unroll") for (int ni = 0; ni < 4; ++ni)                 \
                acc[mh * 4 + m4][ni] = __builtin_amdgcn_mfma_f32_16x16x32_bf16( \
                    af[m4], bfr[ni], acc[mh * 4 + m4][ni], 0, 0, 0);         \
        __builtin_amdgcn_s_setprio(0);                                       \
      }                                                                      \
    }                                                                        \
  }

  STAGE(0, 0);  // prologue: tile 0 -> buf0
#pragma unroll
  for (int t = 0; t < NT - 1; ++t) {
    STAGE((t + 1) & 1, t + 1);                       // prefetch t+1
    asm volatile("s_waitcnt vmcnt(8)" ::: "memory"); // tile t landed (8 newer ok)
    __builtin_amdgcn_s_barrier();                    // collective visibility
    COMPUTE(t & 1);
    __builtin_amdgcn_s_barrier();                    // done reading buf[t&1]
  }
  asm volatile("s_waitcnt vmcnt(0)" ::: "memory");
  __builtin_amdgcn_s_barrier();
  COMPUTE((NT - 1) & 1);

#undef STAGE
#undef COMPUTE

  // epilogue: C/D layout col = lane&15, row = (lane>>4)*4 + reg  [m89]
  size_t obase = (size_t)e * M_TOT * ND;
  int row0 = mt * BM + wm * 128;
  int col0 = nt * BN + wn * 64;
#pragma unroll
  for (int mi = 0; mi < 8; ++mi)
#pragma unroll
    for (int ni = 0; ni < 4; ++ni) {
      int r0 = row0 + mi * 16 + lk * 4;
      int c = col0 + ni * 16 + lr;
      float* op = out + obase + (size_t)r0 * ND + c;
#pragma unroll
      for (int q = 0; q < 4; ++q) op[(size_t)q * ND] = acc[mi][ni][q];
    }
}

extern "C" void kernel_launch(void* const* d_in, const int* in_sizes, int n_in,
                              void* d_out, int out_size, void* d_ws, size_t ws_size,
                              hipStream_t stream) {
  const float* x = (const float*)d_in[0];        // [B][S][D] f32
  const float* theta = (const float*)d_in[1];    // [E][R] f32
  const float* proj_w = (const float*)d_in[2];   // [E][D][D] f32
  float* out = (float*)d_out;                    // [E][B][S][D] f32

  __hip_bfloat16* xb = (__hip_bfloat16*)d_ws;                          // 16 MB
  __hip_bfloat16* Wb = (__hip_bfloat16*)((char*)d_ws +
                        (size_t)M_TOT * D_ * sizeof(__hip_bfloat16));  // 4 MB

  hipLaunchKernelGGL(build_w_rot, dim3(E_), dim3(512), 0, stream,
                     theta, proj_w, Wb);
  constexpr int NX = M_TOT * D_ / 4;
  constexpr int NW = E_ * D_ * D_ / 4;
  hipLaunchKernelGGL(conv_fused, dim3((NX + NW) / 256), dim3(256), 0, stream,
                     x, proj_w, xb, Wb);
  hipLaunchKernelGGL(gemm_xw, dim3(E_ * (M_TOT / 256) * (D_ / 256)), dim3(512),
                     0, stream, xb, Wb, out);
}

// Round 4
// 142.061 us; speedup vs baseline: 1.1774x; 1.1774x over previous
//
#include <hip/hip_runtime.h>
#include <hip/hip_bf16.h>

#define E_ 8
#define B_ 8
#define S_ 2048
#define D_ 512
#define R_ 128
#define M_TOT (B_ * S_)   // 16384

typedef __attribute__((ext_vector_type(8))) short bf16x8;
typedef __attribute__((ext_vector_type(4))) float f32x4;

__device__ __forceinline__ void gload_lds16(void* lds, const void* g) {
  __builtin_amdgcn_global_load_lds(
      (const __attribute__((address_space(1))) void*)g,
      (__attribute__((address_space(3))) void*)lds, 16, 0, 0);
}

// ---------------------------------------------------------------------------
// Kernel 1: W[e] cols 0..128 = rotation-touched part of proj_w[e] @ Rm[e].
// All Givens planes are (0, k+1) -> per-row recurrence over k.
// ---------------------------------------------------------------------------
__global__ __launch_bounds__(512) void build_w_rot(
    const float* __restrict__ theta, const float* __restrict__ pw,
    __hip_bfloat16* __restrict__ Wb) {
  int e = blockIdx.x;
  int t = threadIdx.x;  // 0..511 = row
  __shared__ float cs[R_], ss[R_];
  __shared__ float Pch[512][33];            // +1 pad: conflict-free
  __shared__ __hip_bfloat16 Wch[512][34];   // 17-dword stride: 2-way max
  if (t < R_) {
    float a = tanhf(theta[e * R_ + t]) * 0.1f;
    cs[t] = cosf(a);
    ss[t] = sinf(a);
  }
  const float* Pe = pw + (size_t)e * D_ * D_;
  __hip_bfloat16* We = Wb + (size_t)e * D_ * D_;
  float u = Pe[(size_t)t * D_];  // P[t][0]
  __syncthreads();
  for (int c = 0; c < 4; ++c) {
    for (int i = t; i < 512 * 32; i += 512) {
      int row = i >> 5, col = i & 31;
      Pch[row][col] = Pe[(size_t)row * D_ + 1 + 32 * c + col];
    }
    __syncthreads();
#pragma unroll
    for (int kk = 0; kk < 32; ++kk) {
      int k = 32 * c + kk;
      float pj = Pch[t][kk];
      Wch[t][kk] = __float2bfloat16(cs[k] * pj - ss[k] * u);
      u = cs[k] * u + ss[k] * pj;
    }
    __syncthreads();
    for (int i = t; i < 512 * 32; i += 512) {
      int row = i >> 5, col = i & 31;
      We[(size_t)row * D_ + 1 + 32 * c + col] = Wch[row][col];
    }
    __syncthreads();
  }
  We[(size_t)t * D_] = __float2bfloat16(u);
}

// ---------------------------------------------------------------------------
// Kernel 2 (fused): x f32->bf16 (float4) + W tail cols 129..511 from proj_w.
// ---------------------------------------------------------------------------
__global__ void conv_fused(const float* __restrict__ x,
                           const float* __restrict__ pw,
                           __hip_bfloat16* __restrict__ xb,
                           __hip_bfloat16* __restrict__ Wb) {
  constexpr int NX = M_TOT * D_ / 4;   // x float4 groups
  int i = blockIdx.x * blockDim.x + threadIdx.x;
  if (i < NX) {
    float4 v = ((const float4*)x)[i];
    union { short4 s; __hip_bfloat16 h[4]; } u;
    u.h[0] = __float2bfloat16(v.x);
    u.h[1] = __float2bfloat16(v.y);
    u.h[2] = __float2bfloat16(v.z);
    u.h[3] = __float2bfloat16(v.w);
    ((short4*)xb)[i] = u.s;
  } else {
    int g = i - NX;                    // over E*D*D/4 groups
    int gidx = g & 127;                // group within a row; d = gidx*4..+3
    if (gidx < 32) return;             // d <= 127: owned by build_w_rot
    float4 v = ((const float4*)pw)[g];
    union { short4 s; __hip_bfloat16 h[4]; } u;
    u.h[0] = __float2bfloat16(v.x);
    u.h[1] = __float2bfloat16(v.y);
    u.h[2] = __float2bfloat16(v.z);
    u.h[3] = __float2bfloat16(v.w);
    if (gidx > 32) {
      ((short4*)Wb)[g] = u.s;          // d = 132..511 region, full group
    } else {                           // gidx==32: d=128..131, write 129..131
      Wb[(size_t)g * 4 + 1] = u.h[1];
      Wb[(size_t)g * 4 + 2] = u.h[2];
      Wb[(size_t)g * 4 + 3] = u.h[3];
    }
  }
}

// ---------------------------------------------------------------------------
// Kernel 3: out[e] = Xb @ Wb[e]^T  (NT GEMM). 256x256 tile, BK=32, 8 waves.
// 4-slot LDS ring, counted vmcnt (T3/T4), setprio (T5), XCD swizzle (T1).
// T2: involutive chunk swizzle slot = chunk ^ ((row>>1)&3), applied on the
// staging SOURCE (within each row's 64B group -> coalescing kept) and on the
// fragment READ (uniform 8 lanes per 16B slot -> conflict-free b128).
// ---------------------------------------------------------------------------
__global__ __launch_bounds__(512, 2) void gemm_xw(
    const __hip_bfloat16* __restrict__ Xb,   // [M_TOT][512]
    const __hip_bfloat16* __restrict__ Wb,   // [E][512][512] rows=o, cols=d
    float* __restrict__ out)                 // [E][M_TOT][512]
{
  constexpr int BM = 256, BN = 256, BK = 32;
  constexpr int KD = D_, ND = D_;
  constexpr int NT = KD / BK;  // 16
  __shared__ __align__(16) __hip_bfloat16 As[4][BM * BK];  // 64 KB
  __shared__ __align__(16) __hip_bfloat16 Bs[4][BN * BK];  // 64 KB

  // T1: bijective XCD-chunked swizzle, mt-major (A-panel + W reuse per XCD).
  int bx = blockIdx.x;                 // 1024 blocks, 1024%8==0
  int swz = (bx & 7) * 128 + (bx >> 3);
  int mt = swz >> 4;          // 0..63
  int e  = (swz >> 1) & 7;    // 0..7
  int nt = swz & 1;           // 0..1

  int tid = threadIdx.x;
  int wave = tid >> 6, lane = tid & 63;
  int lr = lane & 15, lk = lane >> 4;
  int wm = wave >> 2, wn = wave & 3;   // 2 x 4 waves, each owns 128x64 of C

  const __hip_bfloat16* Ag = Xb + (size_t)(mt * BM) * KD;
  const __hip_bfloat16* Bg = Wb + ((size_t)e * ND + (size_t)nt * BN) * KD;

  // staging source geometry: lane -> (row = lane>>2, chunk permuted in-row)
  int srow = lane >> 2;
  int scol = ((lane & 3) ^ ((lane >> 3) & 3)) * 8;

  // fragment read bases: chunk slot = lk ^ ((row>>1)&3), row ~ lr mod 16
  int cterm = (lk ^ ((lr >> 1) & 3)) * 8;
  int aoff = (wm * 128 + lr) * BK + cterm;
  int boff = (wn * 64 + lr) * BK + cterm;

  f32x4 acc[8][4];
#pragma unroll
  for (int i = 0; i < 8; ++i)
#pragma unroll
    for (int j = 0; j < 4; ++j) acc[i][j] = (f32x4){0.f, 0.f, 0.f, 0.f};

  // stage tile t into ring slot: wave covers rows [(wave*2+i)*16, +16)
#define STAGE(slot, t)                                                       \
  {                                                                          \
    _Pragma("unroll") for (int i = 0; i < 2; ++i) {                          \
      int rbase = (wave * 2 + i) * 16;                                       \
      gload_lds16(&As[slot][rbase * BK],                                     \
                  Ag + (size_t)(rbase + srow) * KD + (t) * BK + scol);       \
      gload_lds16(&Bs[slot][rbase * BK],                                     \
                  Bg + (size_t)(rbase + srow) * KD + (t) * BK + scol);       \
    }                                                                        \
  }

#define COMPUTE(slot)                                                        \
  {                                                                          \
    bf16x8 bfr[4], af[8];                                                    \
    _Pragma("unroll") for (int ni = 0; ni < 4; ++ni)                         \
        bfr[ni] = *(const bf16x8*)&Bs[slot][boff + ni * 16 * BK];            \
    _Pragma("unroll") for (int mi = 0; mi < 8; ++mi)                         \
        af[mi] = *(const bf16x8*)&As[slot][aoff + mi * 16 * BK];             \
    __builtin_amdgcn_s_setprio(1);                                           \
    _Pragma("unroll") for (int mi = 0; mi < 8; ++mi)                         \
        _Pragma("unroll") for (int ni = 0; ni < 4; ++ni)                     \
            acc[mi][ni] = __builtin_amdgcn_mfma_f32_16x16x32_bf16(           \
                af[mi], bfr[ni], acc[mi][ni], 0, 0, 0);                      \
    __builtin_amdgcn_s_setprio(0);                                           \
  }

  STAGE(0, 0);
  STAGE(1, 1);
  STAGE(2, 2);
#pragma unroll
  for (int t = 0; t < NT; ++t) {
    // tile t complete; keep newer tiles' loads (4 issues each) in flight
    if (t < NT - 2) {
      asm volatile("s_waitcnt vmcnt(8)" ::: "memory");
    } else if (t == NT - 2) {
      asm volatile("s_waitcnt vmcnt(4)" ::: "memory");
    } else {
      asm volatile("s_waitcnt vmcnt(0)" ::: "memory");
    }
    __builtin_amdgcn_s_barrier();        // tile t visible to all waves
    asm volatile("" ::: "memory");
    if (t + 3 < NT) STAGE((t + 3) & 3, t + 3);  // slot idle since iter t-1
    COMPUTE(t & 3);
    asm volatile("" ::: "memory");
    __builtin_amdgcn_s_barrier();        // done reading slot t&3
    asm volatile("" ::: "memory");
  }

#undef STAGE
#undef COMPUTE

  // epilogue: C/D layout col = lane&15, row = (lane>>4)*4 + reg  [m89]
  size_t obase = (size_t)e * M_TOT * ND;
  int row0 = mt * BM + wm * 128;
  int col0 = nt * BN + wn * 64;
#pragma unroll
  for (int mi = 0; mi < 8; ++mi)
#pragma unroll
    for (int ni = 0; ni < 4; ++ni) {
      int r0 = row0 + mi * 16 + lk * 4;
      int c = col0 + ni * 16 + lr;
      float* op = out + obase + (size_t)r0 * ND + c;
#pragma unroll
      for (int q = 0; q < 4; ++q) op[(size_t)q * ND] = acc[mi][ni][q];
    }
}

extern "C" void kernel_launch(void* const* d_in, const int* in_sizes, int n_in,
                              void* d_out, int out_size, void* d_ws, size_t ws_size,
                              hipStream_t stream) {
  const float* x = (const float*)d_in[0];        // [B][S][D] f32
  const float* theta = (const float*)d_in[1];    // [E][R] f32
  const float* proj_w = (const float*)d_in[2];   // [E][D][D] f32
  float* out = (float*)d_out;                    // [E][B][S][D] f32

  __hip_bfloat16* xb = (__hip_bfloat16*)d_ws;                          // 16 MB
  __hip_bfloat16* Wb = (__hip_bfloat16*)((char*)d_ws +
                        (size_t)M_TOT * D_ * sizeof(__hip_bfloat16));  // 4 MB

  hipLaunchKernelGGL(build_w_rot, dim3(E_), dim3(512), 0, stream,
                     theta, proj_w, Wb);
  constexpr int NX = M_TOT * D_ / 4;
  constexpr int NW = E_ * D_ * D_ / 4;
  hipLaunchKernelGGL(conv_fused, dim3((NX + NW) / 256), dim3(256), 0, stream,
                     x, proj_w, xb, Wb);
  hipLaunchKernelGGL(gemm_xw, dim3(E_ * (M_TOT / 256) * (D_ / 256)), dim3(512),
                     0, stream, xb, Wb, out);
}

// Round 5
// 130.486 us; speedup vs baseline: 1.2819x; 1.0887x over previous
//
#include <hip/hip_runtime.h>
#include <hip/hip_bf16.h>

#define E_ 8
#define B_ 8
#define S_ 2048
#define D_ 512
#define R_ 128
#define M_TOT (B_ * S_)   // 16384

typedef __attribute__((ext_vector_type(8))) short bf16x8;
typedef __attribute__((ext_vector_type(4))) float f32x4;

__device__ __forceinline__ void gload_lds16(void* lds, const void* g) {
  __builtin_amdgcn_global_load_lds(
      (const __attribute__((address_space(1))) void*)g,
      (__attribute__((address_space(3))) void*)lds, 16, 0, 0);
}

// ---------------------------------------------------------------------------
// Fused prep kernel. Grid roles (rot first so its serial chains start early):
//   [0,16)           rotation recurrence: W[e] cols 0..128, 256 rows/block
//   [16,2064)        W tail cols 129..511 = bf16(proj_w)
//   [2064,6160)      x f32 -> bf16 (2 float4 groups per thread)
// All three are independent; fusing removes 2 launches + serialization.
// ---------------------------------------------------------------------------
#define ROT_B 16
#define WT_B 2048
#define CX_B 4096
__global__ __launch_bounds__(256) void prep_fused(
    const float* __restrict__ x, const float* __restrict__ theta,
    const float* __restrict__ pw, __hip_bfloat16* __restrict__ xb,
    __hip_bfloat16* __restrict__ Wb) {
  int blk = blockIdx.x;
  int t = threadIdx.x;
  if (blk < ROT_B) {
    // ---- rotation: all Givens planes are (0,k+1) -> per-row recurrence ----
    __shared__ float cs[R_], ss[R_];
    __shared__ float Pch[256][17];            // 17-stride: conflict-free
    __shared__ __hip_bfloat16 Wch[256][18];
    int e = blk >> 1;
    int r0 = (blk & 1) * 256;
    if (t < R_) {
      float a = tanhf(theta[e * R_ + t]) * 0.1f;
      cs[t] = cosf(a);
      ss[t] = sinf(a);
    }
    const float* Pe = pw + (size_t)e * D_ * D_;
    __hip_bfloat16* We = Wb + (size_t)e * D_ * D_;
    float u = Pe[(size_t)(r0 + t) * D_];  // P[r][0]
    __syncthreads();
    for (int c = 0; c < 8; ++c) {  // 16 k-columns per chunk
      for (int i = t; i < 256 * 16; i += 256) {
        int row = i >> 4, col = i & 15;
        Pch[row][col] = Pe[(size_t)(r0 + row) * D_ + 1 + 16 * c + col];
      }
      __syncthreads();
#pragma unroll
      for (int kk = 0; kk < 16; ++kk) {
        int k = 16 * c + kk;
        float pj = Pch[t][kk];
        Wch[t][kk] = __float2bfloat16(cs[k] * pj - ss[k] * u);
        u = cs[k] * u + ss[k] * pj;
      }
      __syncthreads();
      for (int i = t; i < 256 * 16; i += 256) {
        int row = i >> 4, col = i & 15;
        We[(size_t)(r0 + row) * D_ + 1 + 16 * c + col] = Wch[row][col];
      }
      __syncthreads();
    }
    We[(size_t)(r0 + t) * D_] = __float2bfloat16(u);
  } else if (blk < ROT_B + WT_B) {
    // ---- W tail: cols 129..511 ----
    int g = (blk - ROT_B) * 256 + t;   // group over E*D*D/4
    int gidx = g & 127;                // d = gidx*4 .. +3
    if (gidx < 32) return;             // d <= 127 owned by rotation
    float4 v = ((const float4*)pw)[g];
    union { short4 s; __hip_bfloat16 h[4]; } u;
    u.h[0] = __float2bfloat16(v.x);
    u.h[1] = __float2bfloat16(v.y);
    u.h[2] = __float2bfloat16(v.z);
    u.h[3] = __float2bfloat16(v.w);
    if (gidx > 32) {
      ((short4*)Wb)[g] = u.s;
    } else {  // d = 128..131 -> write 129..131 only
      Wb[(size_t)g * 4 + 1] = u.h[1];
      Wb[(size_t)g * 4 + 2] = u.h[2];
      Wb[(size_t)g * 4 + 3] = u.h[3];
    }
  } else {
    // ---- x conversion: 2 float4 groups per thread ----
    int i = (blk - ROT_B - WT_B) * 256 + t;
#pragma unroll
    for (int rep = 0; rep < 2; ++rep) {
      int idx = i + rep * (CX_B * 256);
      float4 v = ((const float4*)x)[idx];
      union { short4 s; __hip_bfloat16 h[4]; } u;
      u.h[0] = __float2bfloat16(v.x);
      u.h[1] = __float2bfloat16(v.y);
      u.h[2] = __float2bfloat16(v.z);
      u.h[3] = __float2bfloat16(v.w);
      ((short4*)xb)[idx] = u.s;
    }
  }
}

// ---------------------------------------------------------------------------
// GEMM: out[e] = Xb @ Wb[e]^T  (NT). 256x256 tile, BK=32, 8 waves (2Mx4N).
// 4-slot LDS ring + counted vmcnt (T3/T4), involutive chunk swizzle on both
// staging-source and fragment-read (T2), XCD swizzle (T1).
// NEW: each K-tile computed in 2 phases (mh=0/1, 16 MFMA each) with an
// alignment barrier + stage issues interleaved into the phases, setprio
// around each MFMA cluster (T5 needs the phase-split to pay).
// ---------------------------------------------------------------------------
__global__ __launch_bounds__(512, 2) void gemm_xw(
    const __hip_bfloat16* __restrict__ Xb,   // [M_TOT][512]
    const __hip_bfloat16* __restrict__ Wb,   // [E][512][512] rows=o, cols=d
    float* __restrict__ out)                 // [E][M_TOT][512]
{
  constexpr int BM = 256, BN = 256, BK = 32;
  constexpr int KD = D_, ND = D_;
  constexpr int NT = KD / BK;  // 16
  __shared__ __align__(16) __hip_bfloat16 As[4][BM * BK];  // 64 KB
  __shared__ __align__(16) __hip_bfloat16 Bs[4][BN * BK];  // 64 KB

  // T1: bijective XCD-chunked swizzle, mt-major.
  int bx = blockIdx.x;                 // 1024 blocks, 1024%8==0
  int swz = (bx & 7) * 128 + (bx >> 3);
  int mt = swz >> 4;          // 0..63
  int e  = (swz >> 1) & 7;    // 0..7
  int nt = swz & 1;           // 0..1

  int tid = threadIdx.x;
  int wave = tid >> 6, lane = tid & 63;
  int lr = lane & 15, lk = lane >> 4;
  int wm = wave >> 2, wn = wave & 3;   // each wave owns 128x64 of C

  const __hip_bfloat16* Ag = Xb + (size_t)(mt * BM) * KD;
  const __hip_bfloat16* Bg = Wb + ((size_t)e * ND + (size_t)nt * BN) * KD;

  // staging source: row = lane>>2, 16B chunk permuted within the row's 64B
  int srow = lane >> 2;
  int scol = ((lane & 3) ^ ((lane >> 3) & 3)) * 8;
  // fragment read: chunk slot = lk ^ ((row>>1)&3)
  int cterm = (lk ^ ((lr >> 1) & 3)) * 8;
  int aoff = (wm * 128 + lr) * BK + cterm;
  int boff = (wn * 64 + lr) * BK + cterm;

  f32x4 acc[8][4];
#pragma unroll
  for (int i = 0; i < 8; ++i)
#pragma unroll
    for (int j = 0; j < 4; ++j) acc[i][j] = (f32x4){0.f, 0.f, 0.f, 0.f};

#define STAGE_A(slot, t)                                                     \
  {                                                                          \
    _Pragma("unroll") for (int i = 0; i < 2; ++i) {                          \
      int rbase = (wave * 2 + i) * 16;                                       \
      gload_lds16(&As[slot][rbase * BK],                                     \
                  Ag + (size_t)(rbase + srow) * KD + (t) * BK + scol);       \
    }                                                                        \
  }
#define STAGE_B(slot, t)                                                     \
  {                                                                          \
    _Pragma("unroll") for (int i = 0; i < 2; ++i) {                          \
      int rbase = (wave * 2 + i) * 16;                                       \
      gload_lds16(&Bs[slot][rbase * BK],                                     \
                  Bg + (size_t)(rbase + srow) * KD + (t) * BK + scol);       \
    }                                                                        \
  }

  STAGE_A(0, 0); STAGE_B(0, 0);
  STAGE_A(1, 1); STAGE_B(1, 1);
  STAGE_A(2, 2); STAGE_B(2, 2);

#pragma unroll
  for (int t = 0; t < NT; ++t) {
    int slot = t & 3;
    // tile t landed (own-wave count; barrier makes it collective)
    if (t < NT - 2) {
      asm volatile("s_waitcnt vmcnt(8)" ::: "memory");
    } else if (t == NT - 2) {
      asm volatile("s_waitcnt vmcnt(4)" ::: "memory");
    } else {
      asm volatile("s_waitcnt vmcnt(0)" ::: "memory");
    }
    __builtin_amdgcn_s_barrier();   // tile-ready (also ends prev tile)
    asm volatile("" ::: "memory");

    // ---- phase A: B-frags + A-frags(mh=0) | stage A of t+3 | 16 MFMA ----
    bf16x8 bfr[4], af0[4];
#pragma unroll
    for (int ni = 0; ni < 4; ++ni)
      bfr[ni] = *(const bf16x8*)&Bs[slot][boff + ni * 16 * BK];
#pragma unroll
    for (int m4 = 0; m4 < 4; ++m4)
      af0[m4] = *(const bf16x8*)&As[slot][aoff + m4 * 16 * BK];
    if (t + 3 < NT) STAGE_A((t + 3) & 3, t + 3);
    asm volatile("" ::: "memory");
    __builtin_amdgcn_s_barrier();   // phase alignment
    __builtin_amdgcn_s_setprio(1);
#pragma unroll
    for (int m4 = 0; m4 < 4; ++m4)
#pragma unroll
      for (int ni = 0; ni < 4; ++ni)
        acc[m4][ni] = __builtin_amdgcn_mfma_f32_16x16x32_bf16(
            af0[m4], bfr[ni], acc[m4][ni], 0, 0, 0);
    __builtin_amdgcn_s_setprio(0);

    // ---- phase B: A-frags(mh=1) | stage B of t+3 | 16 MFMA ----
    bf16x8 af1[4];
#pragma unroll
    for (int m4 = 0; m4 < 4; ++m4)
      af1[m4] = *(const bf16x8*)&As[slot][aoff + (4 + m4) * 16 * BK];
    if (t + 3 < NT) STAGE_B((t + 3) & 3, t + 3);
    asm volatile("" ::: "memory");
    __builtin_amdgcn_s_barrier();   // phase alignment
    __builtin_amdgcn_s_setprio(1);
#pragma unroll
    for (int m4 = 0; m4 < 4; ++m4)
#pragma unroll
      for (int ni = 0; ni < 4; ++ni)
        acc[4 + m4][ni] = __builtin_amdgcn_mfma_f32_16x16x32_bf16(
            af1[m4], bfr[ni], acc[4 + m4][ni], 0, 0, 0);
    __builtin_amdgcn_s_setprio(0);
    asm volatile("" ::: "memory");
  }

#undef STAGE_A
#undef STAGE_B

  // epilogue: C/D layout col = lane&15, row = (lane>>4)*4 + reg  [m89]
  size_t obase = (size_t)e * M_TOT * ND;
  int row0 = mt * BM + wm * 128;
  int col0 = nt * BN + wn * 64;
#pragma unroll
  for (int mi = 0; mi < 8; ++mi)
#pragma unroll
    for (int ni = 0; ni < 4; ++ni) {
      int r0 = row0 + mi * 16 + lk * 4;
      int c = col0 + ni * 16 + lr;
      float* op = out + obase + (size_t)r0 * ND + c;
#pragma unroll
      for (int q = 0; q < 4; ++q) op[(size_t)q * ND] = acc[mi][ni][q];
    }
}

extern "C" void kernel_launch(void* const* d_in, const int* in_sizes, int n_in,
                              void* d_out, int out_size, void* d_ws, size_t ws_size,
                              hipStream_t stream) {
  const float* x = (const float*)d_in[0];        // [B][S][D] f32
  const float* theta = (const float*)d_in[1];    // [E][R] f32
  const float* proj_w = (const float*)d_in[2];   // [E][D][D] f32
  float* out = (float*)d_out;                    // [E][B][S][D] f32

  __hip_bfloat16* xb = (__hip_bfloat16*)d_ws;                          // 16 MB
  __hip_bfloat16* Wb = (__hip_bfloat16*)((char*)d_ws +
                        (size_t)M_TOT * D_ * sizeof(__hip_bfloat16));  // 4 MB

  hipLaunchKernelGGL(prep_fused, dim3(ROT_B + WT_B + CX_B), dim3(256), 0,
                     stream, x, theta, proj_w, xb, Wb);
  hipLaunchKernelGGL(gemm_xw, dim3(E_ * (M_TOT / 256) * (D_ / 256)), dim3(512),
                     0, stream, xb, Wb, out);
}